// Round 3
// baseline (464.207 us; speedup 1.0000x reference)
//
#include <hip/hip_runtime.h>

#define Bn 8
#define Cn 256
#define Hn 128
#define Wn 128
#define HW (Hn * Wn)          // 16384 = 1<<14
#define NPIX (Bn * Hn * Wn)   // 131072
#define NPAIR (NPIX / 2)      // 65536

typedef float v2f  __attribute__((ext_vector_type(2)));
typedef float v2fu __attribute__((ext_vector_type(2), aligned(4)));  // unaligned-ok float2
typedef float v4f  __attribute__((ext_vector_type(4)));

// ---------------- Kernel 1: offset conv partials ----------------
// 4 horizontal pixels per thread (w0 = 4-aligned). Per channel: 3 rows
// loaded as {edge scalar, float4, edge scalar} = 9 loads / 4 px.
// Channel split CCH x ACROSS blocks (disjoint slices -> no fetch
// amplification). CCH=16 -> 2048 blocks = 8/CU = 32 waves/CU.
// unroll 4: ~36 loads in flight per waitcnt drain (latency hiding).
template <int CCH>
__global__ __launch_bounds__(256, 8) void conv_partial_kernel(
    const float* __restrict__ x, const float* __restrict__ wconv,
    float2* __restrict__ part)
{
    constexpr int CPC = Cn / CCH;
    const int pg    = blockIdx.x & 127;
    const int chunk = blockIdx.x >> 7;
    const int pq = pg * 256 + (int)threadIdx.x;   // 0..32767
    const int w0 = (pq & 31) << 2;
    const int h  = (pq >> 5) & (Hn - 1);
    const int b  = pq >> 12;

    const float* xb = x + ((size_t)(b * Cn + chunk * CPC)) * HW + h * Wn + w0;

    const bool hm = (h > 0), hp = (h < Hn - 1);
    const bool wm = (w0 > 0), wp = (w0 < Wn - 4);

    float a00 = 0.f, a01 = 0.f, a02 = 0.f, a03 = 0.f;   // out ch 0, px 0..3
    float a10 = 0.f, a11 = 0.f, a12 = 0.f, a13 = 0.f;   // out ch 1, px 0..3

    const float* w0b = wconv + chunk * CPC * 9;
    const float* w1b = wconv + Cn * 9 + chunk * CPC * 9;

    #pragma unroll 4
    for (int c = 0; c < CPC; ++c) {
        const float* xc = xb + c * HW;
        float v[3][6];
        #pragma unroll
        for (int r = 0; r < 3; ++r) {
            const float* rp = xc + (r - 1) * Wn;
            const bool vld = (r == 0) ? hm : (r == 2) ? hp : true;
            if (vld) {
                const float4 m = *(const float4*)rp;   // 16B aligned (w0%4==0)
                v[r][0] = wm ? rp[-1] : 0.f;
                v[r][1] = m.x; v[r][2] = m.y; v[r][3] = m.z; v[r][4] = m.w;
                v[r][5] = wp ? rp[4] : 0.f;
            } else {
                v[r][0] = 0.f; v[r][1] = 0.f; v[r][2] = 0.f;
                v[r][3] = 0.f; v[r][4] = 0.f; v[r][5] = 0.f;
            }
        }
        const float* w0c = w0b + c * 9;   // lane-uniform -> s_load
        const float* w1c = w1b + c * 9;
        #pragma unroll
        for (int r = 0; r < 3; ++r) {
            const float k0 = w0c[r*3+0], k1 = w0c[r*3+1], k2 = w0c[r*3+2];
            const float u0 = w1c[r*3+0], u1 = w1c[r*3+1], u2 = w1c[r*3+2];
            a00 = fmaf(v[r][0], k0, a00); a00 = fmaf(v[r][1], k1, a00); a00 = fmaf(v[r][2], k2, a00);
            a01 = fmaf(v[r][1], k0, a01); a01 = fmaf(v[r][2], k1, a01); a01 = fmaf(v[r][3], k2, a01);
            a02 = fmaf(v[r][2], k0, a02); a02 = fmaf(v[r][3], k1, a02); a02 = fmaf(v[r][4], k2, a02);
            a03 = fmaf(v[r][3], k0, a03); a03 = fmaf(v[r][4], k1, a03); a03 = fmaf(v[r][5], k2, a03);
            a10 = fmaf(v[r][0], u0, a10); a10 = fmaf(v[r][1], u1, a10); a10 = fmaf(v[r][2], u2, a10);
            a11 = fmaf(v[r][1], u0, a11); a11 = fmaf(v[r][2], u1, a11); a11 = fmaf(v[r][3], u2, a11);
            a12 = fmaf(v[r][2], u0, a12); a12 = fmaf(v[r][3], u1, a12); a12 = fmaf(v[r][4], u2, a12);
            a13 = fmaf(v[r][3], u0, a13); a13 = fmaf(v[r][4], u1, a13); a13 = fmaf(v[r][5], u2, a13);
        }
    }

    v4f* pt = (v4f*)(part + (size_t)chunk * NPIX + ((size_t)pq << 2));
    v4f s0 = {a00, a10, a01, a11};
    v4f s1 = {a02, a12, a03, a13};
    pt[0] = s0;
    pt[1] = s1;
}

// ---------------- Kernel 1.5: partial reduce + position (in-place) -------
// One thread per pixel pair. Sums the CCH partial float4s, adds bias +
// base grid, clips -> writes final (px0,py0,px1,py1) OVER chunk 0 of part.
// Race-free in place: thread pp reads slots {k*NPAIR+pp}, writes slot pp.
template <int CCH>
__global__ __launch_bounds__(256, 8) void reduce_kernel(
    float2* __restrict__ part, const float* __restrict__ bconv)
{
    const int pp = blockIdx.x * 256 + (int)threadIdx.x;   // 0..NPAIR-1
    v4f* p4 = (v4f*)part;
    v4f q = p4[pp];
    #pragma unroll
    for (int k = 1; k < CCH; ++k) q += p4[(size_t)k * NPAIR + pp];

    const int pr  = pp & (HW / 2 - 1);
    const int hw0 = pr << 1;
    const int w = hw0 & (Wn - 1);
    const int h = hw0 >> 7;

    const float bc0 = bconv[0], bc1 = bconv[1];
    float px0 = (float)h + q.x + bc0;
    float py0 = (float)w + q.y + bc1;
    float px1 = (float)h + q.z + bc0;
    float py1 = (float)(w + 1) + q.w + bc1;
    px0 = fminf(fmaxf(px0, 0.f), (float)(Hn - 2));
    py0 = fminf(fmaxf(py0, 0.f), (float)(Wn - 2));
    px1 = fminf(fmaxf(px1, 0.f), (float)(Hn - 2));
    py1 = fminf(fmaxf(py1, 0.f), (float)(Wn - 2));

    v4f o = {px0, py0, px1, py1};
    p4[pp] = o;
}

// ---------------- Kernel 2: bilinear gather ----------------
// 2 horizontal pixels per thread x 32-channel chunk. Single float4
// pos-load per thread (was CCH float4s); corner pairs loaded as
// unaligned float2; aligned nontemporal float2 stores.
#define SCH 8             // sample channel chunks
#define SPC (Cn / SCH)    // 32 channels per thread

__global__ __launch_bounds__(256, 8) void sample_kernel(
    const float* __restrict__ x, const float2* __restrict__ part,
    float* __restrict__ out)
{
    const int tid = blockIdx.x * 256 + (int)threadIdx.x;
    const int pp    = tid & (NPAIR - 1);
    const int chunk = tid >> 16;            // 0..7
    const int pr  = pp & (HW / 2 - 1);
    const int b   = pp >> 13;
    const int hw0 = pr << 1;

    const v4f q = ((const v4f*)part)[pp];   // px0,py0,px1,py1 (pre-clipped)

    const float fx0 = floorf(q.x), fy0 = floorf(q.y);
    const float fx1 = floorf(q.z), fy1 = floorf(q.w);
    const float dx0 = q.x - fx0, dy0 = q.y - fy0;
    const float dx1 = q.z - fx1, dy1 = q.w - fy1;
    const int bs0 = (int)fx0 * Wn + (int)fy0;
    const int bs1 = (int)fx1 * Wn + (int)fy1;

    const float glt0 = (1.f - dx0) * (1.f - dy0), grb0 = dx0 * dy0;
    const float glb0 = (1.f - dx0) * dy0,         grt0 = dx0 * (1.f - dy0);
    const float glt1 = (1.f - dx1) * (1.f - dy1), grb1 = dx1 * dy1;
    const float glb1 = (1.f - dx1) * dy1,         grt1 = dx1 * (1.f - dy1);

    const size_t cb = ((size_t)(b * Cn + chunk * SPC)) * HW;
    const float* xb = x + cb;
    float* ob = out + cb + hw0;

    #pragma unroll 8
    for (int c = 0; c < SPC; ++c) {
        const float* xc = xb + (size_t)c * HW;
        v2fu A0 = *(const v2fu*)(xc + bs0);        // lt, lb
        v2fu B0 = *(const v2fu*)(xc + bs0 + Wn);   // rt, rb
        v2fu A1 = *(const v2fu*)(xc + bs1);
        v2fu B1 = *(const v2fu*)(xc + bs1 + Wn);
        const float o0 = glt0 * A0.x + glb0 * A0.y + grt0 * B0.x + grb0 * B0.y;
        const float o1 = glt1 * A1.x + glb1 * A1.y + grt1 * B1.x + grb1 * B1.y;
        v2f o = {o0, o1};
        __builtin_nontemporal_store(o, (v2f*)(ob + (size_t)c * HW));
    }
}

extern "C" void kernel_launch(void* const* d_in, const int* in_sizes, int n_in,
                              void* d_out, int out_size, void* d_ws, size_t ws_size,
                              hipStream_t stream) {
    const float* x     = (const float*)d_in[0];
    const float* wconv = (const float*)d_in[1];
    const float* bconv = (const float*)d_in[2];
    float* out = (float*)d_out;

    float2* part = (float2*)d_ws;

    if (ws_size >= (size_t)16 * NPIX * sizeof(float2)) {
        conv_partial_kernel<16><<<128 * 16, 256, 0, stream>>>(x, wconv, part);
        reduce_kernel<16><<<NPAIR / 256, 256, 0, stream>>>(part, bconv);
    } else if (ws_size >= (size_t)8 * NPIX * sizeof(float2)) {
        conv_partial_kernel<8><<<128 * 8, 256, 0, stream>>>(x, wconv, part);
        reduce_kernel<8><<<NPAIR / 256, 256, 0, stream>>>(part, bconv);
    } else {
        conv_partial_kernel<4><<<128 * 4, 256, 0, stream>>>(x, wconv, part);
        reduce_kernel<4><<<NPAIR / 256, 256, 0, stream>>>(part, bconv);
    }
    sample_kernel<<<(NPAIR * SCH) / 256, 256, 0, stream>>>(x, part, out);
}

// Round 4
// 308.852 us; speedup vs baseline: 1.5030x; 1.5030x over previous
//
#include <hip/hip_runtime.h>

#define Bn 8
#define Cn 256
#define Hn 128
#define Wn 128
#define HW (Hn * Wn)          // 16384 = 1<<14
#define NPIX (Bn * Hn * Wn)   // 131072
#define NPAIR (NPIX / 2)      // 65536

typedef float v2f  __attribute__((ext_vector_type(2)));
typedef float v2fu __attribute__((ext_vector_type(2), aligned(4)));  // unaligned-ok float2
typedef float v4f  __attribute__((ext_vector_type(4)));

// ---------------- Kernel 1: offset conv partials ----------------
// 4 horizontal pixels per thread (w0 = 4-aligned). Per channel: 3 rows
// loaded as {edge scalar, float4, edge scalar} = 9 loads / 4 px.
// Channel split CCH x ACROSS blocks (disjoint slices). CCH=16 -> 2048
// blocks = 8/CU = 32 waves/CU.
// NOTE: unroll MUST stay at 2 — unroll 4 under launch_bounds(256,8)
// spills (round 3: WRITE_SIZE 16 MB -> 390 MB, conv 80 -> 243 us).
template <int CCH>
__global__ __launch_bounds__(256, 8) void conv_partial_kernel(
    const float* __restrict__ x, const float* __restrict__ wconv,
    float2* __restrict__ part)
{
    constexpr int CPC = Cn / CCH;
    const int pg    = blockIdx.x & 127;
    const int chunk = blockIdx.x >> 7;
    const int pq = pg * 256 + (int)threadIdx.x;   // 0..32767
    const int w0 = (pq & 31) << 2;
    const int h  = (pq >> 5) & (Hn - 1);
    const int b  = pq >> 12;

    const float* xb = x + ((size_t)(b * Cn + chunk * CPC)) * HW + h * Wn + w0;

    const bool hm = (h > 0), hp = (h < Hn - 1);
    const bool wm = (w0 > 0), wp = (w0 < Wn - 4);

    float a00 = 0.f, a01 = 0.f, a02 = 0.f, a03 = 0.f;   // out ch 0, px 0..3
    float a10 = 0.f, a11 = 0.f, a12 = 0.f, a13 = 0.f;   // out ch 1, px 0..3

    const float* w0b = wconv + chunk * CPC * 9;
    const float* w1b = wconv + Cn * 9 + chunk * CPC * 9;

    #pragma unroll 2
    for (int c = 0; c < CPC; ++c) {
        const float* xc = xb + c * HW;
        float v[3][6];
        #pragma unroll
        for (int r = 0; r < 3; ++r) {
            const float* rp = xc + (r - 1) * Wn;
            const bool vld = (r == 0) ? hm : (r == 2) ? hp : true;
            if (vld) {
                const float4 m = *(const float4*)rp;   // 16B aligned (w0%4==0)
                v[r][0] = wm ? rp[-1] : 0.f;
                v[r][1] = m.x; v[r][2] = m.y; v[r][3] = m.z; v[r][4] = m.w;
                v[r][5] = wp ? rp[4] : 0.f;
            } else {
                v[r][0] = 0.f; v[r][1] = 0.f; v[r][2] = 0.f;
                v[r][3] = 0.f; v[r][4] = 0.f; v[r][5] = 0.f;
            }
        }
        const float* w0c = w0b + c * 9;   // lane-uniform -> s_load
        const float* w1c = w1b + c * 9;
        #pragma unroll
        for (int r = 0; r < 3; ++r) {
            const float k0 = w0c[r*3+0], k1 = w0c[r*3+1], k2 = w0c[r*3+2];
            const float u0 = w1c[r*3+0], u1 = w1c[r*3+1], u2 = w1c[r*3+2];
            a00 = fmaf(v[r][0], k0, a00); a00 = fmaf(v[r][1], k1, a00); a00 = fmaf(v[r][2], k2, a00);
            a01 = fmaf(v[r][1], k0, a01); a01 = fmaf(v[r][2], k1, a01); a01 = fmaf(v[r][3], k2, a01);
            a02 = fmaf(v[r][2], k0, a02); a02 = fmaf(v[r][3], k1, a02); a02 = fmaf(v[r][4], k2, a02);
            a03 = fmaf(v[r][3], k0, a03); a03 = fmaf(v[r][4], k1, a03); a03 = fmaf(v[r][5], k2, a03);
            a10 = fmaf(v[r][0], u0, a10); a10 = fmaf(v[r][1], u1, a10); a10 = fmaf(v[r][2], u2, a10);
            a11 = fmaf(v[r][1], u0, a11); a11 = fmaf(v[r][2], u1, a11); a11 = fmaf(v[r][3], u2, a11);
            a12 = fmaf(v[r][2], u0, a12); a12 = fmaf(v[r][3], u1, a12); a12 = fmaf(v[r][4], u2, a12);
            a13 = fmaf(v[r][3], u0, a13); a13 = fmaf(v[r][4], u1, a13); a13 = fmaf(v[r][5], u2, a13);
        }
    }

    v4f* pt = (v4f*)(part + (size_t)chunk * NPIX + ((size_t)pq << 2));
    v4f s0 = {a00, a10, a01, a11};
    v4f s1 = {a02, a12, a03, a13};
    pt[0] = s0;
    pt[1] = s1;
}

// ---------------- Kernel 1.5: partial reduce + position (in-place) -------
// One thread per pixel pair. Sums the CCH partial float4s, adds bias +
// base grid, clips -> writes final (px0,py0,px1,py1) OVER chunk 0 of part.
// Race-free in place: thread pp reads slots {k*NPAIR+pp, k>=1}, writes pp.
template <int CCH>
__global__ __launch_bounds__(256, 8) void reduce_kernel(
    float2* __restrict__ part, const float* __restrict__ bconv)
{
    const int pp = blockIdx.x * 256 + (int)threadIdx.x;   // 0..NPAIR-1
    v4f* p4 = (v4f*)part;
    v4f q = p4[pp];
    #pragma unroll
    for (int k = 1; k < CCH; ++k) q += p4[(size_t)k * NPAIR + pp];

    const int pr  = pp & (HW / 2 - 1);
    const int hw0 = pr << 1;
    const int w = hw0 & (Wn - 1);
    const int h = hw0 >> 7;

    const float bc0 = bconv[0], bc1 = bconv[1];
    float px0 = (float)h + q.x + bc0;
    float py0 = (float)w + q.y + bc1;
    float px1 = (float)h + q.z + bc0;
    float py1 = (float)(w + 1) + q.w + bc1;
    px0 = fminf(fmaxf(px0, 0.f), (float)(Hn - 2));
    py0 = fminf(fmaxf(py0, 0.f), (float)(Wn - 2));
    px1 = fminf(fmaxf(px1, 0.f), (float)(Hn - 2));
    py1 = fminf(fmaxf(py1, 0.f), (float)(Wn - 2));

    v4f o = {px0, py0, px1, py1};
    p4[pp] = o;
}

// ---------------- Kernel 2: bilinear gather ----------------
// 2 horizontal pixels per thread x 32-channel chunk. Single float4
// pos-load per thread; corner pairs loaded as unaligned float2;
// aligned nontemporal float2 stores.
#define SCH 8             // sample channel chunks
#define SPC (Cn / SCH)    // 32 channels per thread

__global__ __launch_bounds__(256, 8) void sample_kernel(
    const float* __restrict__ x, const float2* __restrict__ part,
    float* __restrict__ out)
{
    const int tid = blockIdx.x * 256 + (int)threadIdx.x;
    const int pp    = tid & (NPAIR - 1);
    const int chunk = tid >> 16;            // 0..7
    const int pr  = pp & (HW / 2 - 1);
    const int b   = pp >> 13;
    const int hw0 = pr << 1;

    const v4f q = ((const v4f*)part)[pp];   // px0,py0,px1,py1 (pre-clipped)

    const float fx0 = floorf(q.x), fy0 = floorf(q.y);
    const float fx1 = floorf(q.z), fy1 = floorf(q.w);
    const float dx0 = q.x - fx0, dy0 = q.y - fy0;
    const float dx1 = q.z - fx1, dy1 = q.w - fy1;
    const int bs0 = (int)fx0 * Wn + (int)fy0;
    const int bs1 = (int)fx1 * Wn + (int)fy1;

    const float glt0 = (1.f - dx0) * (1.f - dy0), grb0 = dx0 * dy0;
    const float glb0 = (1.f - dx0) * dy0,         grt0 = dx0 * (1.f - dy0);
    const float glt1 = (1.f - dx1) * (1.f - dy1), grb1 = dx1 * dy1;
    const float glb1 = (1.f - dx1) * dy1,         grt1 = dx1 * (1.f - dy1);

    const size_t cb = ((size_t)(b * Cn + chunk * SPC)) * HW;
    const float* xb = x + cb;
    float* ob = out + cb + hw0;

    #pragma unroll 8
    for (int c = 0; c < SPC; ++c) {
        const float* xc = xb + (size_t)c * HW;
        v2fu A0 = *(const v2fu*)(xc + bs0);        // lt, lb
        v2fu B0 = *(const v2fu*)(xc + bs0 + Wn);   // rt, rb
        v2fu A1 = *(const v2fu*)(xc + bs1);
        v2fu B1 = *(const v2fu*)(xc + bs1 + Wn);
        const float o0 = glt0 * A0.x + glb0 * A0.y + grt0 * B0.x + grb0 * B0.y;
        const float o1 = glt1 * A1.x + glb1 * A1.y + grt1 * B1.x + grb1 * B1.y;
        v2f o = {o0, o1};
        __builtin_nontemporal_store(o, (v2f*)(ob + (size_t)c * HW));
    }
}

extern "C" void kernel_launch(void* const* d_in, const int* in_sizes, int n_in,
                              void* d_out, int out_size, void* d_ws, size_t ws_size,
                              hipStream_t stream) {
    const float* x     = (const float*)d_in[0];
    const float* wconv = (const float*)d_in[1];
    const float* bconv = (const float*)d_in[2];
    float* out = (float*)d_out;

    float2* part = (float2*)d_ws;

    if (ws_size >= (size_t)16 * NPIX * sizeof(float2)) {
        conv_partial_kernel<16><<<128 * 16, 256, 0, stream>>>(x, wconv, part);
        reduce_kernel<16><<<NPAIR / 256, 256, 0, stream>>>(part, bconv);
    } else if (ws_size >= (size_t)8 * NPIX * sizeof(float2)) {
        conv_partial_kernel<8><<<128 * 8, 256, 0, stream>>>(x, wconv, part);
        reduce_kernel<8><<<NPAIR / 256, 256, 0, stream>>>(part, bconv);
    } else {
        conv_partial_kernel<4><<<128 * 4, 256, 0, stream>>>(x, wconv, part);
        reduce_kernel<4><<<NPAIR / 256, 256, 0, stream>>>(part, bconv);
    }
    sample_kernel<<<(NPAIR * SCH) / 256, 256, 0, stream>>>(x, part, out);
}